// Round 3
// baseline (430.618 us; speedup 1.0000x reference)
//
#include <hip/hip_runtime.h>
#include <hip/hip_bf16.h>
#include <stdint.h>
#include <math.h>

#define NB 16384      // batch
#define NSEQ 32       // sequence length
#define NV 1001       // vocab (V+1)
#define NROWS 32768   // 2 * NB flattened rows

// LDS h-buffer geometry (bytes), R=32 rows per WG
#define CHK 272           // chunk stride (16 rows x 16B + 16B pad)
#define RTG (8 * CHK)     // 2176: row-tile-group stride (8 k-chunks)
#define SPL (2 * RTG)     // 4352: split stride (2 row-tile-groups)
#define HBUF (3 * SPL)    // 13056: one h buffer (3 splits)

typedef __attribute__((ext_vector_type(8))) short bf16x8;
typedef __attribute__((ext_vector_type(4))) float f32x4;

// ---------------- threefry2x32 (JAX-exact) ----------------
__device__ __forceinline__ void tf2x32(uint32_t k0, uint32_t k1,
                                       uint32_t x0, uint32_t x1,
                                       uint32_t& o0, uint32_t& o1) {
  const uint32_t ks0 = k0, ks1 = k1, ks2 = k0 ^ k1 ^ 0x1BD11BDAu;
  x0 += ks0; x1 += ks1;
  const int rA[4] = {13, 15, 26, 6};
  const int rB[4] = {17, 29, 16, 24};
#pragma unroll
  for (int i = 0; i < 4; ++i) { x0 += x1; x1 = (x1 << rA[i]) | (x1 >> (32 - rA[i])); x1 ^= x0; }
  x0 += ks1; x1 += ks2 + 1u;
#pragma unroll
  for (int i = 0; i < 4; ++i) { x0 += x1; x1 = (x1 << rB[i]) | (x1 >> (32 - rB[i])); x1 ^= x0; }
  x0 += ks2; x1 += ks0 + 2u;
#pragma unroll
  for (int i = 0; i < 4; ++i) { x0 += x1; x1 = (x1 << rA[i]) | (x1 >> (32 - rA[i])); x1 ^= x0; }
  x0 += ks0; x1 += ks1 + 3u;
#pragma unroll
  for (int i = 0; i < 4; ++i) { x0 += x1; x1 = (x1 << rB[i]) | (x1 >> (32 - rB[i])); x1 ^= x0; }
  x0 += ks1; x1 += ks2 + 4u;
#pragma unroll
  for (int i = 0; i < 4; ++i) { x0 += x1; x1 = (x1 << rA[i]) | (x1 >> (32 - rA[i])); x1 ^= x0; }
  o0 = x0 + ks2; o1 = x1 + ks0 + 5u;
}

__device__ __forceinline__ float gumbel_from_bits(uint32_t bits) {
  uint32_t fb = (bits >> 9) | 0x3f800000u;
  float u = __uint_as_float(fb) - 1.0f;
  u = fmaxf(u, 1.17549435e-38f);
  return -logf(-logf(u));
}

__device__ __forceinline__ float sigm(float x) { return 1.0f / (1.0f + __expf(-x)); }
__device__ __forceinline__ float tanh_(float x) {
  float e = __expf(2.0f * x);
  return 1.0f - 2.0f / (e + 1.0f);
}

__device__ __forceinline__ float dot64(const float* __restrict__ w, const float* h) {
  float a = 0.f;
#pragma unroll
  for (int k = 0; k < 64; ++k) a = fmaf(w[k], h[k], a);
  return a;
}

// round-to-bf16 (RNE): returns bits, outputs rounded-back float
__device__ __forceinline__ unsigned short bfbits(float x, float& xf) {
  __hip_bfloat16 hb = __float2bfloat16(x);
  xf = __bfloat162float(hb);
  unsigned short u;
  __builtin_memcpy(&u, &hb, 2);
  return u;
}

// packed RNE f32x2 -> bf16x2 (low = a, high = b); per-element identical to
// __float2bfloat16, so the 3-split stays bit-exact vs the scalar path.
__device__ __forceinline__ uint32_t pkbf(float a, float b) {
  __hip_bfloat162 p = __float22bfloat162_rn(make_float2(a, b));
  uint32_t u; __builtin_memcpy(&u, &p, 4);
  return u;
}
__device__ __forceinline__ float lo16f(uint32_t w) { return __uint_as_float(w << 16); }
__device__ __forceinline__ float hi16f(uint32_t w) { return __uint_as_float(w & 0xffff0000u); }

// Team-of-4 categorical sample + logprob (bit-exact since r3 — do not touch)
template <int N>
__device__ __forceinline__ void samp_team(const float* lg, int g, int C,
                                          uint32_t k0, uint32_t k1, int b,
                                          int& sOut, float& lpOut) {
  float m = -__builtin_inff();
#pragma unroll
  for (int i = 0; i < N; ++i) m = fmaxf(m, lg[i]);
  m = fmaxf(m, __shfl_xor(m, 1));
  m = fmaxf(m, __shfl_xor(m, 2));
  float se = 0.f;
#pragma unroll
  for (int i = 0; i < N; ++i) se += expf(lg[i] - m);
  se += __shfl_xor(se, 1);
  se += __shfl_xor(se, 2);
  const float lse = logf(se);
  float bz = -__builtin_inff(), bl = 0.f;
  int bi = 0x7fffffff;
#pragma unroll
  for (int i = 0; i < N; ++i) {
    const int c = g + 4 * i;
    uint32_t o0, o1; tf2x32(k0, k1, 0u, (uint32_t)(b * C + c), o0, o1);
    const float z = lg[i] + gumbel_from_bits(o0 ^ o1);
    if (z > bz || (z == bz && c < bi)) { bz = z; bi = c; bl = lg[i]; }
  }
#pragma unroll
  for (int d = 1; d <= 2; d <<= 1) {
    const float z2 = __shfl_xor(bz, d);
    const int i2 = __shfl_xor(bi, d);
    const float l2 = __shfl_xor(bl, d);
    if (z2 > bz || (z2 == bz && i2 < bi)) { bz = z2; bi = i2; bl = l2; }
  }
  sOut = bi;
  lpOut = (bl - m) - lse;
}

// ---------------- kernel A: packed precompute (identical to r9) ------------
// Gate-interleaved j' = unit*4 + gate (gate order i,f,g,o; torch j = gate*64+unit)
// embedWi[v][j'] = b_ih[j] + b_hh[j] + sum_k embed[v][k]*W_ih[j][k]   (fp32)
// Wsp[(s*256 + j')*64 + m]: m = kc*32 + q*8 + p holds split_s(W[j][k]) with
//   k = kc*32 + q*8 + cmap(p), cmap(p) = (p>>1) + ((p&1)<<2).
__global__ __launch_bounds__(256) void k_prep(
    const float* __restrict__ embed, const float* __restrict__ W_ih,
    const float* __restrict__ W_hh, const float* __restrict__ b_ih,
    const float* __restrict__ b_hh, float* __restrict__ embedWi,
    unsigned short* __restrict__ Wsp) {
  if (blockIdx.x >= NV) {
    int idx = (blockIdx.x - NV) * 256 + threadIdx.x;  // 0..49151
    int s = idx >> 14;
    int rem = idx & 16383;
    int jp = rem >> 6, m = rem & 63;
    int kc = m >> 5, q = (m >> 3) & 3, p = m & 7;
    int k = kc * 32 + q * 8 + ((p >> 1) + ((p & 1) << 2));
    int j = (jp & 3) * 64 + (jp >> 2);
    float w = W_hh[j * 64 + k];
    float f1, f2, f3;
    unsigned short b1 = bfbits(w, f1);
    unsigned short b2 = bfbits(w - f1, f2);
    unsigned short b3 = bfbits(w - f1 - f2, f3);
    Wsp[idx] = (s == 0) ? b1 : (s == 1) ? b2 : b3;
    return;
  }
  __shared__ float er[64];
  int v = blockIdx.x;
  if (threadIdx.x < 64) er[threadIdx.x] = embed[v * 64 + threadIdx.x];
  __syncthreads();
  int jp = threadIdx.x;
  int j = (jp & 3) * 64 + (jp >> 2);
  float a = b_ih[j] + b_hh[j];
#pragma unroll
  for (int k = 0; k < 64; ++k) a = fmaf(W_ih[j * 64 + k], er[k], a);
  embedWi[v * 256 + jp] = a;
}

// ---------------- kernel B: LSTM via MFMA, within-wave pipelined -----------
// r12: occupancy is register-quantized at 2 WGs/CU (true footprint ~112 =
// 56 arch VGPR + 48 AGPR afr; 3 WGs need <=102 — infeasible), so r0/r2 were
// residency-identical and time-identical. The r2 profile (Mfma 30 + VALU 71
// ~= 100, no co-issue) is the within-wave serialization: epilogue(rt) sits
// between MFMA(rt) and read(rt+1), and the compiler can't hoist rt+1's
// ds_reads over rt's ds_writes (hbr/hbw aliasing unproven). r12 reorders:
//   read0 -> MFMA0 -> read1 -> MFMA1 -> epi0 -> epi1 -> writes -> barrier
// so all LDS reads precede all LDS writes, epi0 hides under MFMA1's matrix-
// pipe execution, and the split-pack uses packed cvt (pkbf) — bit-identical
// numerics, ~29 fewer VALU per rt. Peak live ~124 <= 128 budget of (512,4).
// 6 products (drop w2h3, w3h2, w3h3 — all <= 2^-24 rel, fp32-reorder class).
__global__ __launch_bounds__(512, 4) void k_lstm(
    const int* __restrict__ inst0, const int* __restrict__ inst1,
    const float* __restrict__ embedWi, const unsigned short* __restrict__ Wsp,
    float* __restrict__ hT) {
  extern __shared__ char smc[];
  int* idsb = (int*)(smc + 2 * HBUF);

  const int tid = threadIdx.x;
  const int lane = tid & 63;
  const int e8 = tid >> 6;        // wave = j'-eighth 0..7
  const int n15 = lane & 15;
  const int quad = lane >> 4;
  const int blk = blockIdx.x;     // 0..1023
  const int rowbase = blk * 32;   // flat row base
  const int rb = (blk & 511) * 32;
  const int* __restrict__ inst = (blk < 512) ? inst0 : inst1;

  // static A-frags: afr[jt][kc][s]; element p = W_s[j'][kc*32+quad*8+cmap(p)]
  bf16x8 afr[2][2][3];
#pragma unroll
  for (int jt = 0; jt < 2; ++jt) {
    const int jrow = (e8 * 2 + jt) * 16 + n15;
#pragma unroll
    for (int kc = 0; kc < 2; ++kc)
#pragma unroll
      for (int s = 0; s < 3; ++s)
        afr[jt][kc][s] =
            *(const bf16x8*)(Wsp + ((s * 256 + jrow) * 64 + kc * 32 + quad * 8));
  }

  for (int i = tid; i < HBUF / 4; i += 512) ((float*)smc)[i] = 0.f;  // zero buf 0
  if (tid < 32) idsb[tid] = inst[(rb + tid) * NSEQ];

  float cst[4];   // cells: [jt][rt] -> jt*2+rt
#pragma unroll
  for (int i = 0; i < 4; ++i) cst[i] = 0.f;

  __syncthreads();

#pragma unroll 1
  for (int t = 0; t < NSEQ; ++t) {
    const char* __restrict__ hbr = smc + (t & 1) * HBUF;
    char* __restrict__ hbw = smc + ((t & 1) ^ 1) * HBUF;
    const bool last = (t == NSEQ - 1);

    if (tid < 32 && t + 1 < NSEQ)
      idsb[((t + 1) & 1) * 32 + tid] = inst[(rb + tid) * NSEQ + t + 1];

    // es for rt0
    float4 esc[2];
    {
      const int v0 = idsb[(t & 1) * 32 + n15];
#pragma unroll
      for (int jt = 0; jt < 2; ++jt)
        esc[jt] = *(const float4*)(embedWi + v0 * 256 +
                                   (e8 * 8 + jt * 4 + quad) * 4);
    }

    // ---- read bfr(rt0) ----
    bf16x8 b0[2][3];
#pragma unroll
    for (int kc = 0; kc < 2; ++kc)
#pragma unroll
      for (int s = 0; s < 3; ++s)
        b0[kc][s] = *(const bf16x8*)(hbr + s * SPL + 0 * RTG +
                                     (kc * 4 + quad) * CHK + n15 * 16);

    // ---- MFMA rt0 -> A0 (same product order/accumulation chain as r10) ----
    f32x4 A0[2];
#pragma unroll
    for (int jt = 0; jt < 2; ++jt) A0[jt] = (f32x4){0.f, 0.f, 0.f, 0.f};
#pragma unroll
    for (int jt = 0; jt < 2; ++jt) {
#pragma unroll
      for (int kc = 0; kc < 2; ++kc) {
        f32x4 acc = A0[jt];
        acc = __builtin_amdgcn_mfma_f32_16x16x32_bf16(afr[jt][kc][0], b0[kc][2], acc, 0, 0, 0);
        acc = __builtin_amdgcn_mfma_f32_16x16x32_bf16(afr[jt][kc][2], b0[kc][0], acc, 0, 0, 0);
        acc = __builtin_amdgcn_mfma_f32_16x16x32_bf16(afr[jt][kc][1], b0[kc][1], acc, 0, 0, 0);
        acc = __builtin_amdgcn_mfma_f32_16x16x32_bf16(afr[jt][kc][0], b0[kc][1], acc, 0, 0, 0);
        acc = __builtin_amdgcn_mfma_f32_16x16x32_bf16(afr[jt][kc][1], b0[kc][0], acc, 0, 0, 0);
        acc = __builtin_amdgcn_mfma_f32_16x16x32_bf16(afr[jt][kc][0], b0[kc][0], acc, 0, 0, 0);
        A0[jt] = acc;
      }
    }

    // ---- read bfr(rt1) (before any LDS writes this timestep) ----
    bf16x8 b1[2][3];
#pragma unroll
    for (int kc = 0; kc < 2; ++kc)
#pragma unroll
      for (int s = 0; s < 3; ++s)
        b1[kc][s] = *(const bf16x8*)(hbr + s * SPL + 1 * RTG +
                                     (kc * 4 + quad) * CHK + n15 * 16);

    // es for rt1 (global, latency covered by MFMA1 + epi0)
    float4 esn[2];
    {
      const int vn = idsb[(t & 1) * 32 + 16 + n15];
#pragma unroll
      for (int jt = 0; jt < 2; ++jt)
        esn[jt] = *(const float4*)(embedWi + vn * 256 +
                                   (e8 * 8 + jt * 4 + quad) * 4);
    }

    // ---- MFMA rt1 -> A1 (matrix pipe busy while epi0's VALU runs) ----
    f32x4 A1[2];
#pragma unroll
    for (int jt = 0; jt < 2; ++jt) A1[jt] = (f32x4){0.f, 0.f, 0.f, 0.f};
#pragma unroll
    for (int jt = 0; jt < 2; ++jt) {
#pragma unroll
      for (int kc = 0; kc < 2; ++kc) {
        f32x4 acc = A1[jt];
        acc = __builtin_amdgcn_mfma_f32_16x16x32_bf16(afr[jt][kc][0], b1[kc][2], acc, 0, 0, 0);
        acc = __builtin_amdgcn_mfma_f32_16x16x32_bf16(afr[jt][kc][2], b1[kc][0], acc, 0, 0, 0);
        acc = __builtin_amdgcn_mfma_f32_16x16x32_bf16(afr[jt][kc][1], b1[kc][1], acc, 0, 0, 0);
        acc = __builtin_amdgcn_mfma_f32_16x16x32_bf16(afr[jt][kc][0], b1[kc][1], acc, 0, 0, 0);
        acc = __builtin_amdgcn_mfma_f32_16x16x32_bf16(afr[jt][kc][1], b1[kc][0], acc, 0, 0, 0);
        acc = __builtin_amdgcn_mfma_f32_16x16x32_bf16(afr[jt][kc][0], b1[kc][0], acc, 0, 0, 0);
        A1[jt] = acc;
      }
    }

    // ---- epilogue rt0: 2 cells, packed 3-split, writes to hbw ----
    {
      float hv0, hv1;
      {
        const float gi = A0[0].x + esc[0].x;
        const float gf = A0[0].y + esc[0].y;
        const float gg = A0[0].z + esc[0].z;
        const float go = A0[0].w + esc[0].w;
        const float ci = sigm(gf) * cst[0] + sigm(gi) * tanh_(gg);
        cst[0] = ci;
        hv0 = sigm(go) * tanh_(ci);
      }
      {
        const float gi = A0[1].x + esc[1].x;
        const float gf = A0[1].y + esc[1].y;
        const float gg = A0[1].z + esc[1].z;
        const float go = A0[1].w + esc[1].w;
        const float ci = sigm(gf) * cst[2] + sigm(gi) * tanh_(gg);
        cst[2] = ci;
        hv1 = sigm(go) * tanh_(ci);
      }
      const uint32_t w1 = pkbf(hv0, hv1);
      float d0 = hv0 - lo16f(w1), d1 = hv1 - hi16f(w1);
      const uint32_t w2 = pkbf(d0, d1);
      d0 -= lo16f(w2); d1 -= hi16f(w2);
      const uint32_t w3 = pkbf(d0, d1);
      char* base = hbw + 0 * RTG + e8 * CHK + n15 * 16 + quad * 4;
      *(uint32_t*)(base + 0 * SPL) = w1;
      *(uint32_t*)(base + 1 * SPL) = w2;
      *(uint32_t*)(base + 2 * SPL) = w3;
      if (last) {
        hT[(e8 * 8 + 0 * 4 + quad) * NROWS + rowbase + 0 * 16 + n15] = hv0;
        hT[(e8 * 8 + 1 * 4 + quad) * NROWS + rowbase + 0 * 16 + n15] = hv1;
      }
    }

    // ---- epilogue rt1 ----
    {
      float hv0, hv1;
      {
        const float gi = A1[0].x + esn[0].x;
        const float gf = A1[0].y + esn[0].y;
        const float gg = A1[0].z + esn[0].z;
        const float go = A1[0].w + esn[0].w;
        const float ci = sigm(gf) * cst[1] + sigm(gi) * tanh_(gg);
        cst[1] = ci;
        hv0 = sigm(go) * tanh_(ci);
      }
      {
        const float gi = A1[1].x + esn[1].x;
        const float gf = A1[1].y + esn[1].y;
        const float gg = A1[1].z + esn[1].z;
        const float go = A1[1].w + esn[1].w;
        const float ci = sigm(gf) * cst[3] + sigm(gi) * tanh_(gg);
        cst[3] = ci;
        hv1 = sigm(go) * tanh_(ci);
      }
      const uint32_t w1 = pkbf(hv0, hv1);
      float d0 = hv0 - lo16f(w1), d1 = hv1 - hi16f(w1);
      const uint32_t w2 = pkbf(d0, d1);
      d0 -= lo16f(w2); d1 -= hi16f(w2);
      const uint32_t w3 = pkbf(d0, d1);
      char* base = hbw + 1 * RTG + e8 * CHK + n15 * 16 + quad * 4;
      *(uint32_t*)(base + 0 * SPL) = w1;
      *(uint32_t*)(base + 1 * SPL) = w2;
      *(uint32_t*)(base + 2 * SPL) = w3;
      if (last) {
        hT[(e8 * 8 + 0 * 4 + quad) * NROWS + rowbase + 1 * 16 + n15] = hv0;
        hT[(e8 * 8 + 1 * 4 + quad) * NROWS + rowbase + 1 * 16 + n15] = hv1;
      }
    }

    __syncthreads();
  }
}

// ---------------- kernel C: heads, 4-lane team per row (bit-exact r3+) -----
__global__ __launch_bounds__(256) void k_heads(
    const int* __restrict__ canvas0, const int* __restrict__ canvas1,
    const int* __restrict__ ref,
    const float* __restrict__ Wc, const float* __restrict__ bc,
    const float* __restrict__ Ws, const float* __restrict__ bs,
    const float* __restrict__ Wl, const float* __restrict__ bl,
    const float* __restrict__ Wr1, const float* __restrict__ br1,
    const float* __restrict__ Wr2, const float* __restrict__ br2,
    const float* __restrict__ Wp, const float* __restrict__ bp,
    const float* __restrict__ hT, float* __restrict__ out) {
  const int tid = threadIdx.x;
  const int g = tid & 3;
  const int s = blockIdx.x & 1;
  const int b = (blockIdx.x >> 1) * 64 + (tid >> 2);
  const float NEG = -__builtin_inff();

  uint32_t kk0[7], kk1[7];
#pragma unroll
  for (int i = 0; i < 7; ++i) {
    uint32_t o0, o1; tf2x32(0u, 42u, 0u, (uint32_t)i, o0, o1);
    kk0[i] = o0; kk1[i] = o1;
  }

  float h[64];
#pragma unroll
  for (int u = 0; u < 64; ++u) h[u] = hT[u * NROWS + s * NB + b];

  float lgc[1], lgs[1];
  lgc[0] = (g < 3) ? (bc[g] + dot64(Wc + g * 64, h)) : NEG;
  lgs[0] = (g < 3) ? (bs[g] + dot64(Ws + g * 64, h)) : NEG;

  if (s == 0) {
    int cs0, ss0, loc0; float clp0, slp0, llp0;
    samp_team<1>(lgc, g, 3, kk0[0], kk1[0], b, cs0, clp0);
    samp_team<1>(lgs, g, 3, kk0[1], kk1[1], b, ss0, slp0);
    float lgl[7];
#pragma unroll
    for (int i = 0; i < 7; ++i) {
      const int cc = g + 4 * i;
      lgl[i] = (cc < 25) ? (bl[cc] + dot64(Wl + cc * 64, h)) : NEG;
    }
    samp_team<7>(lgl, g, 25, kk0[2], kk1[2], b, loc0, llp0);

    if (g == 0) {
      const int p0 = min(max(loc0, 0), 24);
      const int4 pt = ((const int4*)(canvas1 + b * 100))[p0];
      const bool ok0 = (loc0 >= 0) && (loc0 < 25) && (pt.x + pt.y + pt.z + pt.w >= 0);
      const float loc_r0 = ok0 ? 1.f : -1.f;
      const float col_r0 = ok0 ? ((cs0 == pt.x) ? 1.f : -1.f) : 0.f;
      out[0 * NB + b] = clp0;
      out[1 * NB + b] = slp0;
      out[2 * NB + b] = llp0;
      out[7 * NB + b] = loc_r0;
      out[8 * NB + b] = col_r0;
      out[9 * NB + b] = loc_r0;
    }
  } else {
    int cs1, ss1, ls1; float clp1, slp1, llp1;
    samp_team<1>(lgc, g, 3, kk0[3], kk1[3], b, cs1, clp1);
    samp_team<1>(lgs, g, 3, kk0[4], kk1[4], b, ss1, slp1);
    float lgp[2];
#pragma unroll
    for (int i = 0; i < 2; ++i) {
      const int cc = g + 4 * i;
      lgp[i] = bp[cc] + dot64(Wp + cc * 64, h);
    }
    samp_team<2>(lgp, g, 8, kk0[5], kk1[5], b, ls1, llp1);

    float uv8[8], w64[8], w65[8], w66[8], w67[8], wr2[8];
#pragma unroll
    for (int i = 0; i < 8; ++i) {
      const int j = g + 4 * i;
      uv8[i] = br1[j] + dot64(Wr1 + j * 68, h);
      const float* wr = Wr1 + j * 68 + 64;
      w64[i] = wr[0]; w65[i] = wr[1]; w66[i] = wr[2]; w67[i] = wr[3];
      wr2[i] = Wr2[j];
    }
    float lgA[7];
#pragma unroll
    for (int i = 0; i < 7; ++i) lgA[i] = NEG;
    const float b2 = br2[0];
#pragma unroll
    for (int p = 0; p < 25; ++p) {
      const int4 c4 = ((const int4*)(canvas0 + b * 100))[p];
      const float f0 = (float)c4.x, f1 = (float)c4.y;
      const float f2 = (float)c4.z, f3 = (float)c4.w;
      float part = 0.f;
#pragma unroll
      for (int i = 0; i < 8; ++i) {
        float hj = uv8[i];
        hj = fmaf(w64[i], f0, hj);
        hj = fmaf(w65[i], f1, hj);
        hj = fmaf(w66[i], f2, hj);
        hj = fmaf(w67[i], f3, hj);
        part = fmaf(wr2[i], fmaxf(hj, 0.f), part);
      }
      part += __shfl_xor(part, 1);
      part += __shfl_xor(part, 2);
      const float ap = b2 + part;
      if ((p & 3) == g) lgA[p >> 2] = ap;
    }
    int att_s; float alp1;
    samp_team<7>(lgA, g, 25, kk0[6], kk1[6], b, att_s, alp1);

    if (g == 0) {
      const int4 r4 = ((const int4*)(canvas0 + b * 100))[att_s];
      const int4 rr = *(const int4*)(ref + b * 4);
      const bool match = (r4.x == rr.x) && (r4.y == rr.y) &&
                         (r4.z == rr.z) && (r4.w == rr.w);
      const float att_reward = match ? 1.f : -1.f;
      const int ox = (int)((0x22001120u >> (ls1 * 4)) & 0xFu) - 1;
      const int oy = (int)((0x20200211u >> (ls1 * 4)) & 0xFu) - 1;
      const int loc1 = (r4.z + ox) * 5 + (r4.w + oy);
      const int p1 = min(max(loc1, 0), 24);
      const int4 q4 = ((const int4*)(canvas1 + b * 100))[p1];
      const bool ok1 = (loc1 >= 0) && (loc1 < 25) && (q4.x + q4.y + q4.z + q4.w >= 0);
      const float loc_r1 = ok1 ? 1.f : -1.f;
      const float col_r1 = ok1 ? ((cs1 == q4.x) ? 1.f : -1.f) : 0.f;
      out[3 * NB + b]  = clp1;
      out[4 * NB + b]  = slp1;
      out[5 * NB + b]  = llp1;
      out[6 * NB + b]  = alp1;
      out[10 * NB + b] = loc_r1;
      out[11 * NB + b] = col_r1;
      out[12 * NB + b] = loc_r1;
      out[13 * NB + b] = att_reward;
    }
  }
}

extern "C" void kernel_launch(void* const* d_in, const int* in_sizes, int n_in,
                              void* d_out, int out_size, void* d_ws, size_t ws_size,
                              hipStream_t stream) {
  const int* inst0 = (const int*)d_in[0];
  const int* inst1 = (const int*)d_in[1];
  const int* canvas0 = (const int*)d_in[2];
  const int* canvas1 = (const int*)d_in[3];
  const int* ref = (const int*)d_in[4];
  const float* embed = (const float*)d_in[5];
  const float* W_ih = (const float*)d_in[6];
  const float* W_hh = (const float*)d_in[7];
  const float* b_ih = (const float*)d_in[8];
  const float* b_hh = (const float*)d_in[9];
  const float* Wc = (const float*)d_in[10];
  const float* bc = (const float*)d_in[11];
  const float* Ws = (const float*)d_in[12];
  const float* bs = (const float*)d_in[13];
  const float* Wl = (const float*)d_in[14];
  const float* bl = (const float*)d_in[15];
  const float* Wr1 = (const float*)d_in[16];
  const float* br1 = (const float*)d_in[17];
  const float* Wr2 = (const float*)d_in[18];
  const float* br2 = (const float*)d_in[19];
  const float* Wp = (const float*)d_in[20];
  const float* bp = (const float*)d_in[21];

  float* ws = (float*)d_ws;
  float* embedWi = ws;                               // 1001*256 fp32
  unsigned short* Wsp = (unsigned short*)(ws + NV * 256);  // 3*256*64 bf16
  float* hT = ws + NV * 256 + 24576;                 // 64*32768 fp32
  float* out = (float*)d_out;

  const size_t ldsBytes = 2 * HBUF + 256;  // h dbuf (26112) + ids
  k_prep<<<NV + 192, 256, 0, stream>>>(embed, W_ih, W_hh, b_ih, b_hh, embedWi, Wsp);
  k_lstm<<<1024, 512, ldsBytes, stream>>>(inst0, inst1, embedWi, Wsp, hT);
  k_heads<<<512, 256, 0, stream>>>(canvas0, canvas1, ref, Wc, bc, Ws, bs,
                                   Wl, bl, Wr1, br1, Wr2, br2, Wp, bp, hT, out);
}

// Round 4
// 423.277 us; speedup vs baseline: 1.0173x; 1.0173x over previous
//
#include <hip/hip_runtime.h>
#include <hip/hip_bf16.h>
#include <stdint.h>
#include <math.h>

#define NB 16384      // batch
#define NSEQ 32       // sequence length
#define NV 1001       // vocab (V+1)
#define NROWS 32768   // 2 * NB flattened rows

// LDS h-buffer geometry (bytes), R=32 rows per WG
#define CHK 272           // chunk stride (16 rows x 16B + 16B pad)
#define RTG (8 * CHK)     // 2176: row-tile-group stride (8 k-chunks)
#define SPL (2 * RTG)     // 4352: split stride (2 row-tile-groups)
#define HBUF (3 * SPL)    // 13056: one h buffer (3 splits)

typedef __attribute__((ext_vector_type(8))) short bf16x8;
typedef __attribute__((ext_vector_type(4))) float f32x4;

// ---------------- threefry2x32 (JAX-exact) ----------------
__device__ __forceinline__ void tf2x32(uint32_t k0, uint32_t k1,
                                       uint32_t x0, uint32_t x1,
                                       uint32_t& o0, uint32_t& o1) {
  const uint32_t ks0 = k0, ks1 = k1, ks2 = k0 ^ k1 ^ 0x1BD11BDAu;
  x0 += ks0; x1 += ks1;
  const int rA[4] = {13, 15, 26, 6};
  const int rB[4] = {17, 29, 16, 24};
#pragma unroll
  for (int i = 0; i < 4; ++i) { x0 += x1; x1 = (x1 << rA[i]) | (x1 >> (32 - rA[i])); x1 ^= x0; }
  x0 += ks1; x1 += ks2 + 1u;
#pragma unroll
  for (int i = 0; i < 4; ++i) { x0 += x1; x1 = (x1 << rB[i]) | (x1 >> (32 - rB[i])); x1 ^= x0; }
  x0 += ks2; x1 += ks0 + 2u;
#pragma unroll
  for (int i = 0; i < 4; ++i) { x0 += x1; x1 = (x1 << rA[i]) | (x1 >> (32 - rA[i])); x1 ^= x0; }
  x0 += ks0; x1 += ks1 + 3u;
#pragma unroll
  for (int i = 0; i < 4; ++i) { x0 += x1; x1 = (x1 << rB[i]) | (x1 >> (32 - rB[i])); x1 ^= x0; }
  x0 += ks1; x1 += ks2 + 4u;
#pragma unroll
  for (int i = 0; i < 4; ++i) { x0 += x1; x1 = (x1 << rA[i]) | (x1 >> (32 - rA[i])); x1 ^= x0; }
  o0 = x0 + ks2; o1 = x1 + ks0 + 5u;
}

__device__ __forceinline__ float gumbel_from_bits(uint32_t bits) {
  uint32_t fb = (bits >> 9) | 0x3f800000u;
  float u = __uint_as_float(fb) - 1.0f;
  u = fmaxf(u, 1.17549435e-38f);
  return -logf(-logf(u));
}

__device__ __forceinline__ float sigm(float x) { return 1.0f / (1.0f + __expf(-x)); }
__device__ __forceinline__ float tanh_(float x) {
  float e = __expf(2.0f * x);
  return 1.0f - 2.0f / (e + 1.0f);
}

__device__ __forceinline__ float dot64(const float* __restrict__ w, const float* h) {
  float a = 0.f;
#pragma unroll
  for (int k = 0; k < 64; ++k) a = fmaf(w[k], h[k], a);
  return a;
}

// round-to-bf16 (RNE): returns bits, outputs rounded-back float
__device__ __forceinline__ unsigned short bfbits(float x, float& xf) {
  __hip_bfloat16 hb = __float2bfloat16(x);
  xf = __bfloat162float(hb);
  unsigned short u;
  __builtin_memcpy(&u, &hb, 2);
  return u;
}

// packed RNE f32x2 -> bf16x2 (low = a, high = b); per-element identical to
// __float2bfloat16, so the 3-split stays bit-exact vs the scalar path.
__device__ __forceinline__ uint32_t pkbf(float a, float b) {
  __hip_bfloat162 p = __float22bfloat162_rn(make_float2(a, b));
  uint32_t u; __builtin_memcpy(&u, &p, 4);
  return u;
}
__device__ __forceinline__ float lo16f(uint32_t w) { return __uint_as_float(w << 16); }
__device__ __forceinline__ float hi16f(uint32_t w) { return __uint_as_float(w & 0xffff0000u); }

// LSTM cell epilogue — float expressions identical to r3 (bit-exact path)
__device__ __forceinline__ float lcell(const f32x4 A, const float4 es, float& c) {
  const float gi = A.x + es.x;
  const float gf = A.y + es.y;
  const float gg = A.z + es.z;
  const float go = A.w + es.w;
  const float ci = sigm(gf) * c + sigm(gi) * tanh_(gg);
  c = ci;
  return sigm(go) * tanh_(ci);
}

// Team-of-4 categorical sample + logprob (bit-exact since r3 — do not touch)
template <int N>
__device__ __forceinline__ void samp_team(const float* lg, int g, int C,
                                          uint32_t k0, uint32_t k1, int b,
                                          int& sOut, float& lpOut) {
  float m = -__builtin_inff();
#pragma unroll
  for (int i = 0; i < N; ++i) m = fmaxf(m, lg[i]);
  m = fmaxf(m, __shfl_xor(m, 1));
  m = fmaxf(m, __shfl_xor(m, 2));
  float se = 0.f;
#pragma unroll
  for (int i = 0; i < N; ++i) se += expf(lg[i] - m);
  se += __shfl_xor(se, 1);
  se += __shfl_xor(se, 2);
  const float lse = logf(se);
  float bz = -__builtin_inff(), bl = 0.f;
  int bi = 0x7fffffff;
#pragma unroll
  for (int i = 0; i < N; ++i) {
    const int c = g + 4 * i;
    uint32_t o0, o1; tf2x32(k0, k1, 0u, (uint32_t)(b * C + c), o0, o1);
    const float z = lg[i] + gumbel_from_bits(o0 ^ o1);
    if (z > bz || (z == bz && c < bi)) { bz = z; bi = c; bl = lg[i]; }
  }
#pragma unroll
  for (int d = 1; d <= 2; d <<= 1) {
    const float z2 = __shfl_xor(bz, d);
    const int i2 = __shfl_xor(bi, d);
    const float l2 = __shfl_xor(bl, d);
    if (z2 > bz || (z2 == bz && i2 < bi)) { bz = z2; bi = i2; bl = l2; }
  }
  sOut = bi;
  lpOut = (bl - m) - lse;
}

// ---------------- kernel A: packed precompute (identical to r9) ------------
// Gate-interleaved j' = unit*4 + gate (gate order i,f,g,o; torch j = gate*64+unit)
// embedWi[v][j'] = b_ih[j] + b_hh[j] + sum_k embed[v][k]*W_ih[j][k]   (fp32)
// Wsp[(s*256 + j')*64 + m]: m = kc*32 + q*8 + p holds split_s(W[j][k]) with
//   k = kc*32 + q*8 + cmap(p), cmap(p) = (p>>1) + ((p&1)<<2).
__global__ __launch_bounds__(256) void k_prep(
    const float* __restrict__ embed, const float* __restrict__ W_ih,
    const float* __restrict__ W_hh, const float* __restrict__ b_ih,
    const float* __restrict__ b_hh, float* __restrict__ embedWi,
    unsigned short* __restrict__ Wsp) {
  if (blockIdx.x >= NV) {
    int idx = (blockIdx.x - NV) * 256 + threadIdx.x;  // 0..49151
    int s = idx >> 14;
    int rem = idx & 16383;
    int jp = rem >> 6, m = rem & 63;
    int kc = m >> 5, q = (m >> 3) & 3, p = m & 7;
    int k = kc * 32 + q * 8 + ((p >> 1) + ((p & 1) << 2));
    int j = (jp & 3) * 64 + (jp >> 2);
    float w = W_hh[j * 64 + k];
    float f1, f2, f3;
    unsigned short b1 = bfbits(w, f1);
    unsigned short b2 = bfbits(w - f1, f2);
    unsigned short b3 = bfbits(w - f1 - f2, f3);
    Wsp[idx] = (s == 0) ? b1 : (s == 1) ? b2 : b3;
    return;
  }
  __shared__ float er[64];
  int v = blockIdx.x;
  if (threadIdx.x < 64) er[threadIdx.x] = embed[v * 64 + threadIdx.x];
  __syncthreads();
  int jp = threadIdx.x;
  int j = (jp & 3) * 64 + (jp >> 2);
  float a = b_ih[j] + b_hh[j];
#pragma unroll
  for (int k = 0; k < 64; ++k) a = fmaf(W_ih[j * 64 + k], er[k], a);
  embedWi[v * 256 + jp] = a;
}

// ---------------- kernel B: LSTM via MFMA, SGB-interleaved -----------------
// r13: r3's source reorder gave +2% because waves issue IN-ORDER: epilogue
// VALU sits after the MFMA block in the stream, so a wave stalled on a matrix
// -pipe slot can't issue it, and the per-timestep barrier phase-locks all
// waves into the same phase (Mfma 31 + VALU 74 ~ sum-not-max). r13 forces
// static interleave via sched_group_barrier: body split into 4x12-MFMA
// blocks (a00,a01,a10,a11) with each cell epilogue one block behind its
// accumulator; SGB pattern = {MFMA1,DS_READ1}x12 then {MFMA1,VALU4}x36.
// Branch-free body: all 32x32 ids pre-staged to LDS (transposed); final hT
// reconstructed post-loop from the 3-split words (f1+f2+f3 is EXACT — each
// residual is exactly representable in bf16 — so bit-exactness holds).
// Float expression set and MFMA chain order identical to r3.
// 6 products (drop w2h3, w3h2, w3h3 — all <= 2^-24 rel, fp32-reorder class).
__global__ __launch_bounds__(512, 4) void k_lstm(
    const int* __restrict__ inst0, const int* __restrict__ inst1,
    const float* __restrict__ embedWi, const unsigned short* __restrict__ Wsp,
    float* __restrict__ hT) {
  extern __shared__ char smc[];
  int* idst = (int*)(smc + 2 * HBUF);  // [t][row] 32x32 ints (4KB)

  const int tid = threadIdx.x;
  const int lane = tid & 63;
  const int e8 = tid >> 6;        // wave = j'-eighth 0..7
  const int n15 = lane & 15;
  const int quad = lane >> 4;
  const int blk = blockIdx.x;     // 0..1023
  const int rowbase = blk * 32;   // flat row base
  const int rb = (blk & 511) * 32;
  const int* __restrict__ inst = (blk < 512) ? inst0 : inst1;

  // static A-frags: afr[jt][kc][s]; element p = W_s[j'][kc*32+quad*8+cmap(p)]
  bf16x8 afr[2][2][3];
#pragma unroll
  for (int jt = 0; jt < 2; ++jt) {
    const int jrow = (e8 * 2 + jt) * 16 + n15;
#pragma unroll
    for (int kc = 0; kc < 2; ++kc)
#pragma unroll
      for (int s = 0; s < 3; ++s)
        afr[jt][kc][s] =
            *(const bf16x8*)(Wsp + ((s * 256 + jrow) * 64 + kc * 32 + quad * 8));
  }

  for (int i = tid; i < HBUF / 4; i += 512) ((float*)smc)[i] = 0.f;  // zero buf 0

  // pre-stage ALL instruction ids, transposed to [t][row] (coalesced read;
  // one-time 32-way ds_write conflict is irrelevant)
  for (int i = tid; i < 1024; i += 512) {
    const int row = i >> 5, tt = i & 31;
    idst[tt * 32 + row] = inst[rb * NSEQ + i];
  }

  float cst[4];   // cells: [jt][rt] -> jt*2+rt
#pragma unroll
  for (int i = 0; i < 4; ++i) cst[i] = 0.f;

  __syncthreads();

#pragma unroll 1
  for (int t = 0; t < NSEQ; ++t) {
    const char* __restrict__ hbr = smc + (t & 1) * HBUF;
    char* __restrict__ hbw = smc + ((t & 1) ^ 1) * HBUF;

    // ids + es gathers (both rt up front; latency hidden under block 1)
    const int v0 = idst[t * 32 + n15];
    const int vn = idst[t * 32 + 16 + n15];
    float4 esc[2], esn[2];
#pragma unroll
    for (int jt = 0; jt < 2; ++jt) {
      esc[jt] = *(const float4*)(embedWi + v0 * 256 + (e8 * 8 + jt * 4 + quad) * 4);
      esn[jt] = *(const float4*)(embedWi + vn * 256 + (e8 * 8 + jt * 4 + quad) * 4);
    }

    // B-frags rt0 and rt1 (reads precede all LDS writes this timestep)
    bf16x8 b0[2][3], b1[2][3];
#pragma unroll
    for (int kc = 0; kc < 2; ++kc)
#pragma unroll
      for (int s = 0; s < 3; ++s) {
        b0[kc][s] = *(const bf16x8*)(hbr + s * SPL + 0 * RTG +
                                     (kc * 4 + quad) * CHK + n15 * 16);
        b1[kc][s] = *(const bf16x8*)(hbr + s * SPL + 1 * RTG +
                                     (kc * 4 + quad) * CHK + n15 * 16);
      }

    // ---- block 1: a00 (jt0,rt0), 12-MFMA chain (order identical to r3) ----
    f32x4 a00 = (f32x4){0.f, 0.f, 0.f, 0.f};
#pragma unroll
    for (int kc = 0; kc < 2; ++kc) {
      a00 = __builtin_amdgcn_mfma_f32_16x16x32_bf16(afr[0][kc][0], b0[kc][2], a00, 0, 0, 0);
      a00 = __builtin_amdgcn_mfma_f32_16x16x32_bf16(afr[0][kc][2], b0[kc][0], a00, 0, 0, 0);
      a00 = __builtin_amdgcn_mfma_f32_16x16x32_bf16(afr[0][kc][1], b0[kc][1], a00, 0, 0, 0);
      a00 = __builtin_amdgcn_mfma_f32_16x16x32_bf16(afr[0][kc][0], b0[kc][1], a00, 0, 0, 0);
      a00 = __builtin_amdgcn_mfma_f32_16x16x32_bf16(afr[0][kc][1], b0[kc][0], a00, 0, 0, 0);
      a00 = __builtin_amdgcn_mfma_f32_16x16x32_bf16(afr[0][kc][0], b0[kc][0], a00, 0, 0, 0);
    }

    // ---- block 2: a01 (jt1,rt0) ----
    f32x4 a01 = (f32x4){0.f, 0.f, 0.f, 0.f};
#pragma unroll
    for (int kc = 0; kc < 2; ++kc) {
      a01 = __builtin_amdgcn_mfma_f32_16x16x32_bf16(afr[1][kc][0], b0[kc][2], a01, 0, 0, 0);
      a01 = __builtin_amdgcn_mfma_f32_16x16x32_bf16(afr[1][kc][2], b0[kc][0], a01, 0, 0, 0);
      a01 = __builtin_amdgcn_mfma_f32_16x16x32_bf16(afr[1][kc][1], b0[kc][1], a01, 0, 0, 0);
      a01 = __builtin_amdgcn_mfma_f32_16x16x32_bf16(afr[1][kc][0], b0[kc][1], a01, 0, 0, 0);
      a01 = __builtin_amdgcn_mfma_f32_16x16x32_bf16(afr[1][kc][1], b0[kc][0], a01, 0, 0, 0);
      a01 = __builtin_amdgcn_mfma_f32_16x16x32_bf16(afr[1][kc][0], b0[kc][0], a01, 0, 0, 0);
    }
    // cell (jt0,rt0) — interleaves into block 2's MFMA slots via SGB
    const float hv00 = lcell(a00, esc[0], cst[0]);

    // ---- block 3: a10 (jt0,rt1) ----
    f32x4 a10 = (f32x4){0.f, 0.f, 0.f, 0.f};
#pragma unroll
    for (int kc = 0; kc < 2; ++kc) {
      a10 = __builtin_amdgcn_mfma_f32_16x16x32_bf16(afr[0][kc][0], b1[kc][2], a10, 0, 0, 0);
      a10 = __builtin_amdgcn_mfma_f32_16x16x32_bf16(afr[0][kc][2], b1[kc][0], a10, 0, 0, 0);
      a10 = __builtin_amdgcn_mfma_f32_16x16x32_bf16(afr[0][kc][1], b1[kc][1], a10, 0, 0, 0);
      a10 = __builtin_amdgcn_mfma_f32_16x16x32_bf16(afr[0][kc][0], b1[kc][1], a10, 0, 0, 0);
      a10 = __builtin_amdgcn_mfma_f32_16x16x32_bf16(afr[0][kc][1], b1[kc][0], a10, 0, 0, 0);
      a10 = __builtin_amdgcn_mfma_f32_16x16x32_bf16(afr[0][kc][0], b1[kc][0], a10, 0, 0, 0);
    }
    // cell (jt1,rt0) + pack rt0 + rt0 LDS writes
    const float hv10 = lcell(a01, esc[1], cst[2]);
    {
      const uint32_t w1 = pkbf(hv00, hv10);
      float d0 = hv00 - lo16f(w1), d1 = hv10 - hi16f(w1);
      const uint32_t w2 = pkbf(d0, d1);
      d0 -= lo16f(w2); d1 -= hi16f(w2);
      const uint32_t w3 = pkbf(d0, d1);
      char* base = hbw + 0 * RTG + e8 * CHK + n15 * 16 + quad * 4;
      *(uint32_t*)(base + 0 * SPL) = w1;
      *(uint32_t*)(base + 1 * SPL) = w2;
      *(uint32_t*)(base + 2 * SPL) = w3;
    }

    // ---- block 4: a11 (jt1,rt1) ----
    f32x4 a11 = (f32x4){0.f, 0.f, 0.f, 0.f};
#pragma unroll
    for (int kc = 0; kc < 2; ++kc) {
      a11 = __builtin_amdgcn_mfma_f32_16x16x32_bf16(afr[1][kc][0], b1[kc][2], a11, 0, 0, 0);
      a11 = __builtin_amdgcn_mfma_f32_16x16x32_bf16(afr[1][kc][2], b1[kc][0], a11, 0, 0, 0);
      a11 = __builtin_amdgcn_mfma_f32_16x16x32_bf16(afr[1][kc][1], b1[kc][1], a11, 0, 0, 0);
      a11 = __builtin_amdgcn_mfma_f32_16x16x32_bf16(afr[1][kc][0], b1[kc][1], a11, 0, 0, 0);
      a11 = __builtin_amdgcn_mfma_f32_16x16x32_bf16(afr[1][kc][1], b1[kc][0], a11, 0, 0, 0);
      a11 = __builtin_amdgcn_mfma_f32_16x16x32_bf16(afr[1][kc][0], b1[kc][0], a11, 0, 0, 0);
    }
    // cell (jt0,rt1)
    const float hv01 = lcell(a10, esn[0], cst[1]);

    // ---- tail: cell (jt1,rt1) + pack rt1 + rt1 LDS writes ----
    const float hv11 = lcell(a11, esn[1], cst[3]);
    {
      const uint32_t w1 = pkbf(hv01, hv11);
      float d0 = hv01 - lo16f(w1), d1 = hv11 - hi16f(w1);
      const uint32_t w2 = pkbf(d0, d1);
      d0 -= lo16f(w2); d1 -= hi16f(w2);
      const uint32_t w3 = pkbf(d0, d1);
      char* base = hbw + 1 * RTG + e8 * CHK + n15 * 16 + quad * 4;
      *(uint32_t*)(base + 0 * SPL) = w1;
      *(uint32_t*)(base + 1 * SPL) = w2;
      *(uint32_t*)(base + 2 * SPL) = w3;
    }

    // ---- static schedule: masks ALU=0x1 VALU=0x2 SALU=0x4 MFMA=0x8
    //      VMEM_READ=0x20 DS_READ=0x100 DS_WRITE=0x200 ----
    __builtin_amdgcn_sched_group_barrier(0x100, 14, 0);  // idst x2 + b0 x12
    __builtin_amdgcn_sched_group_barrier(0x020, 4, 0);   // esc/esn gathers
#pragma unroll
    for (int i = 0; i < 12; ++i) {                       // block1 || b1 reads
      __builtin_amdgcn_sched_group_barrier(0x008, 1, 0);
      __builtin_amdgcn_sched_group_barrier(0x100, 1, 0);
    }
#pragma unroll
    for (int i = 0; i < 36; ++i) {                       // blocks 2-4 || cells
      __builtin_amdgcn_sched_group_barrier(0x008, 1, 0);
      __builtin_amdgcn_sched_group_barrier(0x002, 4, 0);
    }
    __builtin_amdgcn_sched_group_barrier(0x200, 6, 0);   // h-split writes

    __syncthreads();
  }

  // final h reconstruction from buf0 (t=31 wrote buffer 0): each thread reads
  // back exactly the words it wrote; f1+f2+f3 == h exactly (see header note)
#pragma unroll
  for (int rt = 0; rt < 2; ++rt) {
    const char* base = smc + rt * RTG + e8 * CHK + n15 * 16 + quad * 4;
    const uint32_t w1 = *(const uint32_t*)(base + 0 * SPL);
    const uint32_t w2 = *(const uint32_t*)(base + 1 * SPL);
    const uint32_t w3 = *(const uint32_t*)(base + 2 * SPL);
    const float hv0 = lo16f(w1) + lo16f(w2) + lo16f(w3);
    const float hv1 = hi16f(w1) + hi16f(w2) + hi16f(w3);
    hT[(e8 * 8 + 0 * 4 + quad) * NROWS + rowbase + rt * 16 + n15] = hv0;
    hT[(e8 * 8 + 1 * 4 + quad) * NROWS + rowbase + rt * 16 + n15] = hv1;
  }
}

// ---------------- kernel C: heads, 4-lane team per row (bit-exact r3+) -----
__global__ __launch_bounds__(256) void k_heads(
    const int* __restrict__ canvas0, const int* __restrict__ canvas1,
    const int* __restrict__ ref,
    const float* __restrict__ Wc, const float* __restrict__ bc,
    const float* __restrict__ Ws, const float* __restrict__ bs,
    const float* __restrict__ Wl, const float* __restrict__ bl,
    const float* __restrict__ Wr1, const float* __restrict__ br1,
    const float* __restrict__ Wr2, const float* __restrict__ br2,
    const float* __restrict__ Wp, const float* __restrict__ bp,
    const float* __restrict__ hT, float* __restrict__ out) {
  const int tid = threadIdx.x;
  const int g = tid & 3;
  const int s = blockIdx.x & 1;
  const int b = (blockIdx.x >> 1) * 64 + (tid >> 2);
  const float NEG = -__builtin_inff();

  uint32_t kk0[7], kk1[7];
#pragma unroll
  for (int i = 0; i < 7; ++i) {
    uint32_t o0, o1; tf2x32(0u, 42u, 0u, (uint32_t)i, o0, o1);
    kk0[i] = o0; kk1[i] = o1;
  }

  float h[64];
#pragma unroll
  for (int u = 0; u < 64; ++u) h[u] = hT[u * NROWS + s * NB + b];

  float lgc[1], lgs[1];
  lgc[0] = (g < 3) ? (bc[g] + dot64(Wc + g * 64, h)) : NEG;
  lgs[0] = (g < 3) ? (bs[g] + dot64(Ws + g * 64, h)) : NEG;

  if (s == 0) {
    int cs0, ss0, loc0; float clp0, slp0, llp0;
    samp_team<1>(lgc, g, 3, kk0[0], kk1[0], b, cs0, clp0);
    samp_team<1>(lgs, g, 3, kk0[1], kk1[1], b, ss0, slp0);
    float lgl[7];
#pragma unroll
    for (int i = 0; i < 7; ++i) {
      const int cc = g + 4 * i;
      lgl[i] = (cc < 25) ? (bl[cc] + dot64(Wl + cc * 64, h)) : NEG;
    }
    samp_team<7>(lgl, g, 25, kk0[2], kk1[2], b, loc0, llp0);

    if (g == 0) {
      const int p0 = min(max(loc0, 0), 24);
      const int4 pt = ((const int4*)(canvas1 + b * 100))[p0];
      const bool ok0 = (loc0 >= 0) && (loc0 < 25) && (pt.x + pt.y + pt.z + pt.w >= 0);
      const float loc_r0 = ok0 ? 1.f : -1.f;
      const float col_r0 = ok0 ? ((cs0 == pt.x) ? 1.f : -1.f) : 0.f;
      out[0 * NB + b] = clp0;
      out[1 * NB + b] = slp0;
      out[2 * NB + b] = llp0;
      out[7 * NB + b] = loc_r0;
      out[8 * NB + b] = col_r0;
      out[9 * NB + b] = loc_r0;
    }
  } else {
    int cs1, ss1, ls1; float clp1, slp1, llp1;
    samp_team<1>(lgc, g, 3, kk0[3], kk1[3], b, cs1, clp1);
    samp_team<1>(lgs, g, 3, kk0[4], kk1[4], b, ss1, slp1);
    float lgp[2];
#pragma unroll
    for (int i = 0; i < 2; ++i) {
      const int cc = g + 4 * i;
      lgp[i] = bp[cc] + dot64(Wp + cc * 64, h);
    }
    samp_team<2>(lgp, g, 8, kk0[5], kk1[5], b, ls1, llp1);

    float uv8[8], w64[8], w65[8], w66[8], w67[8], wr2[8];
#pragma unroll
    for (int i = 0; i < 8; ++i) {
      const int j = g + 4 * i;
      uv8[i] = br1[j] + dot64(Wr1 + j * 68, h);
      const float* wr = Wr1 + j * 68 + 64;
      w64[i] = wr[0]; w65[i] = wr[1]; w66[i] = wr[2]; w67[i] = wr[3];
      wr2[i] = Wr2[j];
    }
    float lgA[7];
#pragma unroll
    for (int i = 0; i < 7; ++i) lgA[i] = NEG;
    const float b2 = br2[0];
#pragma unroll
    for (int p = 0; p < 25; ++p) {
      const int4 c4 = ((const int4*)(canvas0 + b * 100))[p];
      const float f0 = (float)c4.x, f1 = (float)c4.y;
      const float f2 = (float)c4.z, f3 = (float)c4.w;
      float part = 0.f;
#pragma unroll
      for (int i = 0; i < 8; ++i) {
        float hj = uv8[i];
        hj = fmaf(w64[i], f0, hj);
        hj = fmaf(w65[i], f1, hj);
        hj = fmaf(w66[i], f2, hj);
        hj = fmaf(w67[i], f3, hj);
        part = fmaf(wr2[i], fmaxf(hj, 0.f), part);
      }
      part += __shfl_xor(part, 1);
      part += __shfl_xor(part, 2);
      const float ap = b2 + part;
      if ((p & 3) == g) lgA[p >> 2] = ap;
    }
    int att_s; float alp1;
    samp_team<7>(lgA, g, 25, kk0[6], kk1[6], b, att_s, alp1);

    if (g == 0) {
      const int4 r4 = ((const int4*)(canvas0 + b * 100))[att_s];
      const int4 rr = *(const int4*)(ref + b * 4);
      const bool match = (r4.x == rr.x) && (r4.y == rr.y) &&
                         (r4.z == rr.z) && (r4.w == rr.w);
      const float att_reward = match ? 1.f : -1.f;
      const int ox = (int)((0x22001120u >> (ls1 * 4)) & 0xFu) - 1;
      const int oy = (int)((0x20200211u >> (ls1 * 4)) & 0xFu) - 1;
      const int loc1 = (r4.z + ox) * 5 + (r4.w + oy);
      const int p1 = min(max(loc1, 0), 24);
      const int4 q4 = ((const int4*)(canvas1 + b * 100))[p1];
      const bool ok1 = (loc1 >= 0) && (loc1 < 25) && (q4.x + q4.y + q4.z + q4.w >= 0);
      const float loc_r1 = ok1 ? 1.f : -1.f;
      const float col_r1 = ok1 ? ((cs1 == q4.x) ? 1.f : -1.f) : 0.f;
      out[3 * NB + b]  = clp1;
      out[4 * NB + b]  = slp1;
      out[5 * NB + b]  = llp1;
      out[6 * NB + b]  = alp1;
      out[10 * NB + b] = loc_r1;
      out[11 * NB + b] = col_r1;
      out[12 * NB + b] = loc_r1;
      out[13 * NB + b] = att_reward;
    }
  }
}

extern "C" void kernel_launch(void* const* d_in, const int* in_sizes, int n_in,
                              void* d_out, int out_size, void* d_ws, size_t ws_size,
                              hipStream_t stream) {
  const int* inst0 = (const int*)d_in[0];
  const int* inst1 = (const int*)d_in[1];
  const int* canvas0 = (const int*)d_in[2];
  const int* canvas1 = (const int*)d_in[3];
  const int* ref = (const int*)d_in[4];
  const float* embed = (const float*)d_in[5];
  const float* W_ih = (const float*)d_in[6];
  const float* W_hh = (const float*)d_in[7];
  const float* b_ih = (const float*)d_in[8];
  const float* b_hh = (const float*)d_in[9];
  const float* Wc = (const float*)d_in[10];
  const float* bc = (const float*)d_in[11];
  const float* Ws = (const float*)d_in[12];
  const float* bs = (const float*)d_in[13];
  const float* Wl = (const float*)d_in[14];
  const float* bl = (const float*)d_in[15];
  const float* Wr1 = (const float*)d_in[16];
  const float* br1 = (const float*)d_in[17];
  const float* Wr2 = (const float*)d_in[18];
  const float* br2 = (const float*)d_in[19];
  const float* Wp = (const float*)d_in[20];
  const float* bp = (const float*)d_in[21];

  float* ws = (float*)d_ws;
  float* embedWi = ws;                               // 1001*256 fp32
  unsigned short* Wsp = (unsigned short*)(ws + NV * 256);  // 3*256*64 bf16
  float* hT = ws + NV * 256 + 24576;                 // 64*32768 fp32
  float* out = (float*)d_out;

  const size_t ldsBytes = 2 * HBUF + 4096;  // h dbuf (26112) + idst (4KB)
  k_prep<<<NV + 192, 256, 0, stream>>>(embed, W_ih, W_hh, b_ih, b_hh, embedWi, Wsp);
  k_lstm<<<1024, 512, ldsBytes, stream>>>(inst0, inst1, embedWi, Wsp, hT);
  k_heads<<<512, 256, 0, stream>>>(canvas0, canvas1, ref, Wc, bc, Ws, bs,
                                   Wl, bl, Wr1, br1, Wr2, br2, Wp, bp, hT, out);
}